// Round 2
// baseline (780.870 us; speedup 1.0000x reference)
//
#include <hip/hip_runtime.h>
#include <cstdint>
#include <cstddef>

#define TOKENS 16384
#define DMODEL 4096
#define NEXP   64
#define NSPLIT 2                    // grid-level k split
#define KSPAN  (DMODEL / NSPLIT)    // 2048 per block
#define KWAVE  (KSPAN / 4)          // 512 per wave (4 waves split k within block)
#define BK     64                   // k per wave per staging step
#define NSTEP  (KWAVE / BK)         // 8
#define XSTRIDE 257                 // staging row stride (257%32==1 -> bank = (lane+k)%32, 2-way free)
#define RSTRIDE 65                  // reduction row stride
#define LDSF    16640               // max(64*257=16448, 4*64*65=16640) floats

// ---------------- kernel 1: W[e][d] -> Wt[d][e] (k-major) ----------------
__global__ __launch_bounds__(256)
void transpose_W(const float* __restrict__ W, float* __restrict__ Wt) {
  __shared__ float tile[64][65];
  const int tid = threadIdx.x;
  const int d0 = blockIdx.x * 64;
#pragma unroll
  for (int p = 0; p < 16; ++p) {
    int c = p * 256 + tid;
    int dl = c & 63, e = c >> 6;
    tile[e][dl] = W[(size_t)e * DMODEL + d0 + dl];
  }
  __syncthreads();
#pragma unroll
  for (int p = 0; p < 16; ++p) {
    int c = p * 256 + tid;
    int e = c & 63, dl = c >> 6;
    Wt[(size_t)(d0 + dl) * NEXP + e] = tile[e][dl];
  }
}

// ---------------- kernel 2: lane=token GEMM, W wave-uniform ----------------
// grid (TOKENS/64, NSPLIT), block 256 (4 waves k-split KSPAN into KWAVE each).
// Each lane owns ONE token and ALL 64 expert accumulators. x comes from LDS
// (1 ds_read_b32 per k -> 128 FLOP), W via wave-uniform float4 loads of the
// L2-resident k-major Wt (scalarizable; no LDS-pipe cost).
__global__ __launch_bounds__(256, 2)
void gemm_partial(const float* __restrict__ x, const float* __restrict__ Wt,
                  float* __restrict__ part) {
  __shared__ float xs[LDSF];
  const int tid  = threadIdx.x;
  const int lane = tid & 63;
  const int wv   = tid >> 6;
  const int t0   = blockIdx.x * 64;
  const int kbase = blockIdx.y * KSPAN;

  // staging decomposition: thread stages (token = p*4+wv, window = (tid>>4)&3, kq = tid&15)
  const int kq   = tid & 15;
  const int wwin = (tid >> 4) & 3;

  float acc[NEXP];
#pragma unroll
  for (int e = 0; e < NEXP; ++e) acc[e] = 0.f;

  // prefetch step 0 into regs (16 float4 = token rows p*4+wv, window wwin)
  const float* xg = x + (size_t)(t0 + wv) * DMODEL + kbase + wwin * KWAVE + kq * 4;
  float4 pre[16];
#pragma unroll
  for (int p = 0; p < 16; ++p)
    pre[p] = *(const float4*)(xg + (size_t)p * 4 * DMODEL);

#pragma unroll 1
  for (int s = 0; s < NSTEP; ++s) {
    __syncthreads();
    // regs -> LDS: bank = (t + 4kq + j)%32 over (kq,wwin) lanes -> <=4-way, cheap
#pragma unroll
    for (int p = 0; p < 16; ++p) {
      float* d = &xs[(p * 4 + wv) * XSTRIDE + wwin * BK + kq * 4];
      d[0] = pre[p].x; d[1] = pre[p].y; d[2] = pre[p].z; d[3] = pre[p].w;
    }
    __syncthreads();
    // prefetch next step (drains at next barrier, ~16k cycles away)
    if (s + 1 < NSTEP) {
#pragma unroll
      for (int p = 0; p < 16; ++p)
        pre[p] = *(const float4*)(xg + (size_t)p * 4 * DMODEL + (s + 1) * BK);
    }
    const float* wb = Wt + (size_t)(kbase + wv * KWAVE + s * BK) * NEXP;
    const float* xr = &xs[lane * XSTRIDE + wv * BK];
#pragma unroll 4
    for (int kk = 0; kk < BK; kk += 4) {
      float xv0 = xr[kk + 0], xv1 = xr[kk + 1], xv2 = xr[kk + 2], xv3 = xr[kk + 3];
      const float* wr = wb + kk * NEXP;
#pragma unroll
      for (int e4 = 0; e4 < 16; ++e4) {
        float4 w0 = *(const float4*)&wr[0 * NEXP + e4 * 4];
        float4 w1 = *(const float4*)&wr[1 * NEXP + e4 * 4];
        float4 w2 = *(const float4*)&wr[2 * NEXP + e4 * 4];
        float4 w3 = *(const float4*)&wr[3 * NEXP + e4 * 4];
        acc[e4 * 4 + 0] += xv0 * w0.x; acc[e4 * 4 + 0] += xv1 * w1.x;
        acc[e4 * 4 + 0] += xv2 * w2.x; acc[e4 * 4 + 0] += xv3 * w3.x;
        acc[e4 * 4 + 1] += xv0 * w0.y; acc[e4 * 4 + 1] += xv1 * w1.y;
        acc[e4 * 4 + 1] += xv2 * w2.y; acc[e4 * 4 + 1] += xv3 * w3.y;
        acc[e4 * 4 + 2] += xv0 * w0.z; acc[e4 * 4 + 2] += xv1 * w1.z;
        acc[e4 * 4 + 2] += xv2 * w2.z; acc[e4 * 4 + 2] += xv3 * w3.z;
        acc[e4 * 4 + 3] += xv0 * w0.w; acc[e4 * 4 + 3] += xv1 * w1.w;
        acc[e4 * 4 + 3] += xv2 * w2.w; acc[e4 * 4 + 3] += xv3 * w3.w;
      }
    }
  }

  // in-block reduction: 4 wave-partials per (token, expert), once per kernel
  __syncthreads();
#pragma unroll
  for (int e = 0; e < NEXP; ++e)
    xs[wv * 4160 + lane * RSTRIDE + e] = acc[e];   // bank (lane+e)%32: 2-way free
  __syncthreads();
  float* pb = part + ((size_t)blockIdx.y * TOKENS + t0) * NEXP;
#pragma unroll
  for (int j = 0; j < 16; ++j) {
    int pair = j * 256 + tid;
    int t = pair >> 6, e = pair & 63;
    float v = xs[0 * 4160 + t * RSTRIDE + e] + xs[1 * 4160 + t * RSTRIDE + e]
            + xs[2 * 4160 + t * RSTRIDE + e] + xs[3 * 4160 + t * RSTRIDE + e];
    pb[(size_t)t * NEXP + e] = v;                  // consecutive lanes -> coalesced
  }
}

// ---------------- kernel 3: reduce halves + bias, top-2, softmax ----------------
__global__ __launch_bounds__(256)
void topk_softmax(const float* __restrict__ part, const float* __restrict__ b,
                  float* __restrict__ out) {
  const int tid = threadIdx.x;
  const int lane = tid & 63;
  const int wv = tid >> 6;
  const int t = blockIdx.x * 4 + wv;

  float v = part[(size_t)t * NEXP + lane]
          + part[(size_t)(TOKENS + t) * NEXP + lane]
          + b[lane];

  // top-1 with lower-index tie-break (matches lax.top_k)
  float m1 = v; int i1 = lane;
#pragma unroll
  for (int off = 32; off > 0; off >>= 1) {
    float ov = __shfl_xor(m1, off, 64);
    int   oi = __shfl_xor(i1, off, 64);
    if (ov > m1 || (ov == m1 && oi < i1)) { m1 = ov; i1 = oi; }
  }
  float v2 = (lane == i1) ? -__builtin_inff() : v;
  float m2 = v2; int i2 = lane;
#pragma unroll
  for (int off = 32; off > 0; off >>= 1) {
    float ov = __shfl_xor(m2, off, 64);
    int   oi = __shfl_xor(i2, off, 64);
    if (ov > m2 || (ov == m2 && oi < i2)) { m2 = ov; i2 = oi; }
  }
  float e = __expf(v - m1);
#pragma unroll
  for (int off = 32; off > 0; off >>= 1) e += __shfl_xor(e, off, 64);

  if (lane == 0) {
    out[(size_t)t * 2 + 0] = (float)i1;
    out[(size_t)t * 2 + 1] = (float)i2;
    float inv = 1.0f / e;
    out[(size_t)TOKENS * 2 + (size_t)t * 2 + 0] = inv;
    out[(size_t)TOKENS * 2 + (size_t)t * 2 + 1] = __expf(m2 - m1) * inv;
  }
}

extern "C" void kernel_launch(void* const* d_in, const int* in_sizes, int n_in,
                              void* d_out, int out_size, void* d_ws, size_t ws_size,
                              hipStream_t stream) {
  const float* x = (const float*)d_in[0];
  const float* W = (const float*)d_in[1];
  const float* b = (const float*)d_in[2];
  float* out = (float*)d_out;

  float* Wt   = (float*)d_ws;                      // 1 MB
  float* part = Wt + (size_t)DMODEL * NEXP;        // 2*16384*64 floats = 8 MB

  hipLaunchKernelGGL(transpose_W, dim3(DMODEL / 64), dim3(256), 0, stream, W, Wt);
  hipLaunchKernelGGL(gemm_partial, dim3(TOKENS / 64, NSPLIT), dim3(256), 0, stream,
                     x, Wt, part);
  hipLaunchKernelGGL(topk_softmax, dim3(TOKENS / 4), dim3(256), 0, stream,
                     part, b, out);
}

// Round 3
// 521.671 us; speedup vs baseline: 1.4969x; 1.4969x over previous
//
#include <hip/hip_runtime.h>
#include <cstdint>
#include <cstddef>

#define TOKENS 16384
#define DMODEL 4096
#define NEXP   64
#define NSPLIT 2                    // grid-level k split
#define KSPAN  (DMODEL / NSPLIT)    // 2048 per block
#define BK     128                  // k per staging step
#define NSTEP  (KSPAN / BK)         // 16
#define XSTRIDE (BK + 1)            // 129, odd -> per-phase conflict-free strided reads

typedef float v16f __attribute__((ext_vector_type(16)));
// constant-address-space view: invariant memory, uniform address -> s_load_dwordx16
typedef const __attribute__((address_space(4))) v16f c4v16f;

// ---------------- kernel 1: W[e][d] -> Wt[d][e] (k-major) ----------------
__global__ __launch_bounds__(256)
void transpose_W(const float* __restrict__ W, float* __restrict__ Wt) {
  __shared__ float tile[64][65];
  const int tid = threadIdx.x;
  const int d0 = blockIdx.x * 64;
#pragma unroll
  for (int p = 0; p < 16; ++p) {
    int c = p * 256 + tid;
    int dl = c & 63, e = c >> 6;
    tile[e][dl] = W[(size_t)e * DMODEL + d0 + dl];
  }
  __syncthreads();
#pragma unroll
  for (int p = 0; p < 16; ++p) {
    int c = p * 256 + tid;
    int e = c & 63, dl = c >> 6;
    Wt[(size_t)(d0 + dl) * NEXP + e] = tile[e][dl];
  }
}

// ---------------- kernel 2: lane=token GEMM, W via s_load_dwordx16 ----------------
// grid (TOKENS/64, NSPLIT), block 256 = 4 waves. Wave wv owns experts
// [16*wv, 16*wv+16). Lane = token. Per k: one s_load_dwordx16 of W (scalar
// pipe, wave-uniform) + ds_read of x + 16 v_fmac(vgpr, sgpr, vgpr).
__global__ __launch_bounds__(256, 2)
void gemm_partial(const float* __restrict__ x, const float* __restrict__ Wt,
                  float* __restrict__ part) {
  __shared__ float xs[64 * XSTRIDE];
  const int tid  = threadIdx.x;
  const int lane = tid & 63;
  const int t0   = blockIdx.x * 64;
  const int kbase = blockIdx.y * KSPAN;
  // expert base: MUST be readfirstlane'd so the W address is provably
  // wave-uniform (compiler can't prove tid>>6 uniform; divergent addr kills SMEM)
  const int e0 = __builtin_amdgcn_readfirstlane((tid >> 6) << 4);

  float acc[16];
#pragma unroll
  for (int j = 0; j < 16; ++j) acc[j] = 0.f;

  // staging decomposition: c = p*256+tid -> row=c>>5 (token), col=c&31 (float4 in k)
  const int srow = tid >> 5;        // rows srow, srow+8, ... srow+56
  const int scol = tid & 31;
  const float* xg = x + (size_t)(t0 + srow) * DMODEL + kbase + scol * 4;

  float4 pre[8];
#pragma unroll
  for (int p = 0; p < 8; ++p)
    pre[p] = *(const float4*)(xg + (size_t)p * 8 * DMODEL);

#pragma unroll 1
  for (int s = 0; s < NSTEP; ++s) {
    __syncthreads();
#pragma unroll
    for (int p = 0; p < 8; ++p) {
      float* d = &xs[(p * 8 + srow) * XSTRIDE + scol * 4];
      d[0] = pre[p].x; d[1] = pre[p].y; d[2] = pre[p].z; d[3] = pre[p].w;
    }
    __syncthreads();
    if (s + 1 < NSTEP) {
#pragma unroll
      for (int p = 0; p < 8; ++p)
        pre[p] = *(const float4*)(xg + (size_t)p * 8 * DMODEL + (s + 1) * BK);
    }
    // uniform scalar base for this step's W (SALU arithmetic only)
    const float* wbase = Wt + (size_t)(kbase + s * BK) * NEXP + e0;
    const float* xr = &xs[lane * XSTRIDE];
#pragma unroll 1
    for (int kk = 0; kk < BK; kk += 4) {
      float4 xq = *(const float4*)&xr[kk];
      v16f w0 = *(c4v16f*)(uintptr_t)(wbase + (size_t)(kk + 0) * NEXP);
      v16f w1 = *(c4v16f*)(uintptr_t)(wbase + (size_t)(kk + 1) * NEXP);
      v16f w2 = *(c4v16f*)(uintptr_t)(wbase + (size_t)(kk + 2) * NEXP);
      v16f w3 = *(c4v16f*)(uintptr_t)(wbase + (size_t)(kk + 3) * NEXP);
#pragma unroll
      for (int j = 0; j < 16; ++j) acc[j] += xq.x * w0[j];
#pragma unroll
      for (int j = 0; j < 16; ++j) acc[j] += xq.y * w1[j];
#pragma unroll
      for (int j = 0; j < 16; ++j) acc[j] += xq.z * w2[j];
#pragma unroll
      for (int j = 0; j < 16; ++j) acc[j] += xq.w * w3[j];
    }
  }

  // epilogue: part[half][t0+lane][e0..e0+15], 64 B contiguous per lane
  float* pb = part + ((size_t)blockIdx.y * TOKENS + t0 + lane) * NEXP + e0;
#pragma unroll
  for (int q = 0; q < 4; ++q) {
    float4 v = make_float4(acc[q * 4 + 0], acc[q * 4 + 1], acc[q * 4 + 2], acc[q * 4 + 3]);
    *(float4*)&pb[q * 4] = v;
  }
}

// ---------------- kernel 3: reduce halves + bias, top-2, softmax ----------------
__global__ __launch_bounds__(256)
void topk_softmax(const float* __restrict__ part, const float* __restrict__ b,
                  float* __restrict__ out) {
  const int tid = threadIdx.x;
  const int lane = tid & 63;
  const int wv = tid >> 6;
  const int t = blockIdx.x * 4 + wv;

  float v = part[(size_t)t * NEXP + lane]
          + part[(size_t)(TOKENS + t) * NEXP + lane]
          + b[lane];

  // top-1 with lower-index tie-break (matches lax.top_k)
  float m1 = v; int i1 = lane;
#pragma unroll
  for (int off = 32; off > 0; off >>= 1) {
    float ov = __shfl_xor(m1, off, 64);
    int   oi = __shfl_xor(i1, off, 64);
    if (ov > m1 || (ov == m1 && oi < i1)) { m1 = ov; i1 = oi; }
  }
  float v2 = (lane == i1) ? -__builtin_inff() : v;
  float m2 = v2; int i2 = lane;
#pragma unroll
  for (int off = 32; off > 0; off >>= 1) {
    float ov = __shfl_xor(m2, off, 64);
    int   oi = __shfl_xor(i2, off, 64);
    if (ov > m2 || (ov == m2 && oi < i2)) { m2 = ov; i2 = oi; }
  }
  float e = __expf(v - m1);
#pragma unroll
  for (int off = 32; off > 0; off >>= 1) e += __shfl_xor(e, off, 64);

  if (lane == 0) {
    out[(size_t)t * 2 + 0] = (float)i1;
    out[(size_t)t * 2 + 1] = (float)i2;
    float inv = 1.0f / e;
    out[(size_t)TOKENS * 2 + (size_t)t * 2 + 0] = inv;
    out[(size_t)TOKENS * 2 + (size_t)t * 2 + 1] = __expf(m2 - m1) * inv;
  }
}

extern "C" void kernel_launch(void* const* d_in, const int* in_sizes, int n_in,
                              void* d_out, int out_size, void* d_ws, size_t ws_size,
                              hipStream_t stream) {
  const float* x = (const float*)d_in[0];
  const float* W = (const float*)d_in[1];
  const float* b = (const float*)d_in[2];
  float* out = (float*)d_out;

  float* Wt   = (float*)d_ws;                      // 1 MB
  float* part = Wt + (size_t)DMODEL * NEXP;        // 8 MB

  hipLaunchKernelGGL(transpose_W, dim3(DMODEL / 64), dim3(256), 0, stream, W, Wt);
  hipLaunchKernelGGL(gemm_partial, dim3(TOKENS / 64, NSPLIT), dim3(256), 0, stream,
                     x, Wt, part);
  hipLaunchKernelGGL(topk_softmax, dim3(TOKENS / 4), dim3(256), 0, stream,
                     part, b, out);
}

// Round 4
// 479.382 us; speedup vs baseline: 1.6289x; 1.0882x over previous
//
#include <hip/hip_runtime.h>
#include <cstdint>
#include <cstddef>

#define TOKENS 16384
#define DMODEL 4096
#define NEXP   64
#define TILE_M 256                 // tokens per block
#define BK     32                  // k per stage step

// ---------------- kernel 1: W[e][d] -> Wt[d][e] (k-major) ----------------
__global__ __launch_bounds__(256)
void transpose_W(const float* __restrict__ W, float* __restrict__ Wt) {
  __shared__ float tile[64][65];
  const int tid = threadIdx.x;
  const int d0 = blockIdx.x * 64;
#pragma unroll
  for (int p = 0; p < 16; ++p) {
    int c = p * 256 + tid;
    int dl = c & 63, e = c >> 6;
    tile[e][dl] = W[(size_t)e * DMODEL + d0 + dl];
  }
  __syncthreads();
#pragma unroll
  for (int p = 0; p < 16; ++p) {
    int c = p * 256 + tid;
    int e = c & 63, dl = c >> 6;
    Wt[(size_t)(d0 + dl) * NEXP + e] = tile[e][dl];
  }
}

// ---------------- kernel 2: 8x8-blocked GEMM, x via LDS / W via L1 ----------------
// Block 256 threads = 4 waves; tile TILE_M tokens x 64 experts; grid.y = k-split.
// Thread (tx=tid&7, ty=tid>>3): tokens ty*8..+8, experts tx*8..+8, acc[8][8].
// Per 4-k chunk: 8 swizzled ds_read_b128 (x) + 8 float4 L1 gathers (W, only 8
// distinct 32B addrs/wave, double-buffered on vmcnt) + 256 v_fmac.
// Per-CU wall @2 waves/SIMD: FMA 512W vs LDS ~380W vs VMEM ~190W -> FMA-bound.
template <int NSPLIT>
__global__ __launch_bounds__(256, 2)
void gemm_partial(const float* __restrict__ x, const float* __restrict__ Wt,
                  float* __restrict__ part) {
  constexpr int KSPAN = DMODEL / NSPLIT;
  constexpr int NSTEP = KSPAN / BK;

  __shared__ float4 xs4[TILE_M * 8];   // 32 KB; granule sg = g ^ ((row>>3)&7)
  const int tid = threadIdx.x;
  const int tx = tid & 7;              // expert group: e0 = tx*8
  const int ty = tid >> 3;             // token group: rows ty*8..+8 (ty 0..31)
  const int t0 = blockIdx.x * TILE_M;
  const int kbase = blockIdx.y * KSPAN;
  const int e0 = tx * 8;

  float acc[8][8];
#pragma unroll
  for (int i = 0; i < 8; ++i)
#pragma unroll
    for (int j = 0; j < 8; ++j) acc[i][j] = 0.f;

  // staging: thread stages rows {p*32+ty}, granule tx (coalesced 128B/8-lanes)
  const float* xg = x + (size_t)(t0 + ty) * DMODEL + kbase + tx * 4;
  float4 pre[8];
#pragma unroll
  for (int p = 0; p < 8; ++p)
    pre[p] = *(const float4*)(xg + (size_t)p * 32 * DMODEL);

  // W double-buffer: chunk = 4 consecutive k, 8 experts -> 8 floats/k = 2 float4
  const float* wtb = Wt + (size_t)e0;
  float4 wc[8];                        // [r*2+h]: k-offset r, expert half h
#pragma unroll
  for (int r = 0; r < 4; ++r) {
    wc[r * 2 + 0] = *(const float4*)(wtb + (size_t)(kbase + r) * NEXP);
    wc[r * 2 + 1] = *(const float4*)(wtb + (size_t)(kbase + r) * NEXP + 4);
  }

#pragma unroll 1
  for (int s = 0; s < NSTEP; ++s) {
    __syncthreads();
#pragma unroll
    for (int p = 0; p < 8; ++p) {
      int row = p * 32 + ty;
      int sg = tx ^ ((row >> 3) & 7);
      xs4[row * 8 + sg] = pre[p];
    }
    __syncthreads();
    if (s + 1 < NSTEP) {
#pragma unroll
      for (int p = 0; p < 8; ++p)
        pre[p] = *(const float4*)(xg + (size_t)p * 32 * DMODEL + (s + 1) * BK);
    }
#pragma unroll
    for (int g = 0; g < 8; ++g) {      // chunk = k in [s*BK+4g, +4)
      // prefetch next chunk's W (vmcnt-counted; drains during this chunk's FMA)
      int knext = kbase + s * BK + (g + 1) * 4;
      if (knext > DMODEL - 4) knext = DMODEL - 4;   // last-block tail clamp
      float4 wn[8];
#pragma unroll
      for (int r = 0; r < 4; ++r) {
        wn[r * 2 + 0] = *(const float4*)(wtb + (size_t)(knext + r) * NEXP);
        wn[r * 2 + 1] = *(const float4*)(wtb + (size_t)(knext + r) * NEXP + 4);
      }
      // x fragments: row ty*8+i, granule g^ty -> 8 distinct bank-groups/wave
      float4 xa[8];
#pragma unroll
      for (int i = 0; i < 8; ++i)
        xa[i] = xs4[(ty * 8 + i) * 8 + (g ^ (ty & 7))];
      const float* w = (const float*)wc;           // [r][j]: w[r*8+j]
#pragma unroll
      for (int i = 0; i < 8; ++i) {
        const float* xv = (const float*)&xa[i];
#pragma unroll
        for (int r = 0; r < 4; ++r)
#pragma unroll
          for (int j = 0; j < 8; ++j)
            acc[i][j] += xv[r] * w[r * 8 + j];
      }
#pragma unroll
      for (int q = 0; q < 8; ++q) wc[q] = wn[q];
    }
  }

  // epilogue: part[by][t0+ty*8+i][e0..e0+7]; lanes tx-consecutive -> 32B coalesced
  float* pb = part + ((size_t)blockIdx.y * TOKENS + t0 + ty * 8) * NEXP + e0;
#pragma unroll
  for (int i = 0; i < 8; ++i) {
    *(float4*)(pb + (size_t)i * NEXP)     = make_float4(acc[i][0], acc[i][1], acc[i][2], acc[i][3]);
    *(float4*)(pb + (size_t)i * NEXP + 4) = make_float4(acc[i][4], acc[i][5], acc[i][6], acc[i][7]);
  }
}

// ---------------- kernel 3: reduce partials + bias, top-2, softmax ----------------
template <int NSPLIT>
__global__ __launch_bounds__(256)
void topk_softmax(const float* __restrict__ part, const float* __restrict__ b,
                  float* __restrict__ out) {
  const int tid = threadIdx.x;
  const int lane = tid & 63;
  const int wv = tid >> 6;
  const int t = blockIdx.x * 4 + wv;

  float v = b[lane];
#pragma unroll
  for (int h = 0; h < NSPLIT; ++h)
    v += part[((size_t)h * TOKENS + t) * NEXP + lane];

  // top-1 with lower-index tie-break (matches lax.top_k)
  float m1 = v; int i1 = lane;
#pragma unroll
  for (int off = 32; off > 0; off >>= 1) {
    float ov = __shfl_xor(m1, off, 64);
    int   oi = __shfl_xor(i1, off, 64);
    if (ov > m1 || (ov == m1 && oi < i1)) { m1 = ov; i1 = oi; }
  }
  float v2 = (lane == i1) ? -__builtin_inff() : v;
  float m2 = v2; int i2 = lane;
#pragma unroll
  for (int off = 32; off > 0; off >>= 1) {
    float ov = __shfl_xor(m2, off, 64);
    int   oi = __shfl_xor(i2, off, 64);
    if (ov > m2 || (ov == m2 && oi < i2)) { m2 = ov; i2 = oi; }
  }
  float e = __expf(v - m1);
#pragma unroll
  for (int off = 32; off > 0; off >>= 1) e += __shfl_xor(e, off, 64);

  if (lane == 0) {
    out[(size_t)t * 2 + 0] = (float)i1;
    out[(size_t)t * 2 + 1] = (float)i2;
    float inv = 1.0f / e;
    out[(size_t)TOKENS * 2 + (size_t)t * 2 + 0] = inv;
    out[(size_t)TOKENS * 2 + (size_t)t * 2 + 1] = __expf(m2 - m1) * inv;
  }
}

template <int NSPLIT>
static void launch_all(const float* x, const float* W, const float* b,
                       float* out, void* d_ws, hipStream_t stream) {
  float* Wt   = (float*)d_ws;                    // 1 MB
  float* part = Wt + (size_t)DMODEL * NEXP;      // NSPLIT * 4 MB
  hipLaunchKernelGGL(transpose_W, dim3(DMODEL / 64), dim3(256), 0, stream, W, Wt);
  hipLaunchKernelGGL(gemm_partial<NSPLIT>, dim3(TOKENS / TILE_M, NSPLIT), dim3(256),
                     0, stream, x, Wt, part);
  hipLaunchKernelGGL(topk_softmax<NSPLIT>, dim3(TOKENS / 4), dim3(256), 0, stream,
                     part, b, out);
}

extern "C" void kernel_launch(void* const* d_in, const int* in_sizes, int n_in,
                              void* d_out, int out_size, void* d_ws, size_t ws_size,
                              hipStream_t stream) {
  const float* x = (const float*)d_in[0];
  const float* W = (const float*)d_in[1];
  const float* b = (const float*)d_in[2];
  float* out = (float*)d_out;

  // workspace-adaptive k-split: part = NSPLIT*4MB + Wt 1MB
  const size_t mb = 1024ull * 1024ull;
  if (ws_size >= 33 * mb)      launch_all<8>(x, W, b, out, d_ws, stream);
  else if (ws_size >= 17 * mb) launch_all<4>(x, W, b, out, d_ws, stream);
  else                         launch_all<2>(x, W, b, out, d_ws, stream);
}